// Round 1
// baseline (1879.375 us; speedup 1.0000x reference)
//
#include <hip/hip_runtime.h>
#include <math.h>

typedef float vf4 __attribute__((ext_vector_type(4)));

constexpr int B = 2, T = 2048, E = 512, NH = 8, HD = 64;
constexpr int BH = B * NH;            // 16
constexpr float SCALE = 0.125f;       // HD^-0.5

// =====================================================================
// GEMM: C[M,N] = A[M,K] @ W[K,N] + bias[N]   (fp32, 64x64 tiles, BK=16)
// 256 threads, each computes a 4x4 micro-tile.
// =====================================================================
__global__ __launch_bounds__(256) void gemm_bias(
    const float* __restrict__ A, const float* __restrict__ W,
    const float* __restrict__ bias, float* __restrict__ C,
    int M, int K, int N)
{
  __shared__ float Ast[16][68];   // A^T tile: [kk][row]
  __shared__ float Bs[16][68];    // W tile:   [kk][col]

  const int tid = threadIdx.x;
  const int tx = tid & 15, ty = tid >> 4;
  const int m0 = blockIdx.y * 64, n0 = blockIdx.x * 64;

  // load mapping
  const int ar = tid >> 2;           // 0..63 (A row within tile)
  const int ak = (tid & 3) * 4;      // 0,4,8,12 (k offset)
  const int bk = tid >> 4;           // 0..15 (k row)
  const int bc = (tid & 15) * 4;     // col offset

  float acc[4][4] = {};

  for (int k0 = 0; k0 < K; k0 += 16) {
    vf4 av = *(const vf4*)&A[(size_t)(m0 + ar) * K + k0 + ak];
    vf4 wv = *(const vf4*)&W[(size_t)(k0 + bk) * N + n0 + bc];
    __syncthreads();   // previous-iteration LDS reads done
    Ast[ak + 0][ar] = av[0];
    Ast[ak + 1][ar] = av[1];
    Ast[ak + 2][ar] = av[2];
    Ast[ak + 3][ar] = av[3];
    *(vf4*)&Bs[bk][bc] = wv;
    __syncthreads();
#pragma unroll
    for (int kk = 0; kk < 16; ++kk) {
      vf4 a = *(const vf4*)&Ast[kk][ty * 4];
      vf4 b = *(const vf4*)&Bs[kk][tx * 4];
#pragma unroll
      for (int i = 0; i < 4; ++i)
#pragma unroll
        for (int j = 0; j < 4; ++j)
          acc[i][j] += a[i] * b[j];
    }
  }

#pragma unroll
  for (int i = 0; i < 4; ++i) {
    size_t row = m0 + ty * 4 + i;
#pragma unroll
    for (int j = 0; j < 4; ++j) {
      int col = n0 + tx * 4 + j;
      C[row * N + col] = acc[i][j] + bias[col];
    }
  }
}

// =====================================================================
// od = Q @ w_od + b_od, then per-(bh,i) window params.
// prm: 6 arrays of [BH*T]: bound_l, bound_r, w_bl, w_br, anchor_l, a_frac
// One block (256 thr) handles 16 rows; thread (r,c) does one od element.
// =====================================================================
__global__ __launch_bounds__(256) void od_params(
    const float* __restrict__ qkv, const float* __restrict__ w_od,
    const float* __restrict__ b_od, float* __restrict__ prm)
{
  __shared__ float od_s[16][16];
  const int tid = threadIdx.x;
  const int r = tid >> 4, c = tid & 15;
  const int row = blockIdx.x * 16 + r;          // 0..B*T-1

  float sum = b_od[c];
  const float* qr = qkv + (size_t)row * (3 * E);   // Q part = cols [0,E)
  for (int k = 0; k < E; k += 4) {
    vf4 q = *(const vf4*)&qr[k];
    sum += q[0] * w_od[(k + 0) * 16 + c]
         + q[1] * w_od[(k + 1) * 16 + c]
         + q[2] * w_od[(k + 2) * 16 + c]
         + q[3] * w_od[(k + 3) * 16 + c];
  }
  od_s[r][c] = sum;
  __syncthreads();

  if (tid < 128) {
    const int rr = tid >> 3, h = tid & 7;
    const int grow = blockIdx.x * 16 + rr;
    const int b = grow / T, i = grow % T;
    float o = od_s[rr][h];
    float d = od_s[rr][h + 8];
    float offset   = tanhf(o) * (float)T;
    float duration = (float)T / (1.0f + expf(-d));   // sigmoid(d)*T
    float anchor = (float)i + offset;
    float start = anchor - duration;
    float end   = anchor + duration;
    float bl = floorf(start);
    float br = ceilf(end);
    float al = floorf(anchor);
    int idx = (b * NH + h) * T + i;
    prm[0 * BH * T + idx] = bl;
    prm[1 * BH * T + idx] = br;
    prm[2 * BH * T + idx] = bl - start;   // in (-1, 0]
    prm[3 * BH * T + idx] = end - br;     // in (-1, 0]
    prm[4 * BH * T + idx] = al;
    prm[5 * BH * T + idx] = anchor - al;  // in [0, 1)
  }
}

// =====================================================================
// Flash-style attention with point weights + window mask.
// Grid: (T/64, BH). Block 256 thr. Online softmax including masked
// positions at -1e8 (matches reference softmax exactly, incl. the
// all-masked -> uniform case).
// =====================================================================
__global__ __launch_bounds__(256) void flash_attn(
    const float* __restrict__ qkv, const float* __restrict__ prm,
    float* __restrict__ attn_out)
{
  __shared__ float Qs[64][68];
  __shared__ float Ks[64][68];
  __shared__ float Vs[64][68];
  __shared__ float SsT[64][68];     // P transposed: [j][i]
  __shared__ float red[64][17];     // row-max / row-sum partials
  __shared__ float m_s[64], l_s[64], alpha_s[64];

  const int tid = threadIdx.x;
  const int tx = tid & 15, ty = tid >> 4;
  const int qt = blockIdx.x, bh = blockIdx.y;
  const int b = bh >> 3, h = bh & 7;
  const int i0 = qt * 64;

  // per-thread row params (rows 4*ty .. 4*ty+3)
  float pbl[4], pbr[4], pwbl[4], pwbr[4], pal[4], paf[4];
#pragma unroll
  for (int d = 0; d < 4; ++d) {
    int idx = bh * T + i0 + ty * 4 + d;
    pbl[d]  = prm[0 * BH * T + idx];
    pbr[d]  = prm[1 * BH * T + idx];
    pwbl[d] = prm[2 * BH * T + idx];
    pwbr[d] = prm[3 * BH * T + idx];
    pal[d]  = prm[4 * BH * T + idx];
    paf[d]  = prm[5 * BH * T + idx];
  }

  if (tid < 64) { m_s[tid] = -3.0e38f; l_s[tid] = 0.0f; }

  // load Q tile (head h): Qs[r][c] = qkv[b, i0+r, h*64+c]
#pragma unroll
  for (int it = 0; it < 4; ++it) {
    int lin = it * 256 + tid;
    int r = lin >> 4, cq = (lin & 15) * 4;
    *(vf4*)&Qs[r][cq] =
        *(const vf4*)&qkv[(size_t)(b * T + i0 + r) * (3 * E) + h * HD + cq];
  }

  float acc[4][4] = {};

  for (int kt = 0; kt < T / 64; ++kt) {
    const int j0 = kt * 64;
    __syncthreads();   // prior-iter Vs/SsT reads done (also Q store->use)
#pragma unroll
    for (int it = 0; it < 4; ++it) {
      int lin = it * 256 + tid;
      int r = lin >> 4, cq = (lin & 15) * 4;
      size_t base = (size_t)(b * T + j0 + r) * (3 * E) + h * HD + cq;
      *(vf4*)&Ks[r][cq] = *(const vf4*)&qkv[base + E];
      *(vf4*)&Vs[r][cq] = *(const vf4*)&qkv[base + 2 * E];
    }
    __syncthreads();

    // ---- S = Q K^T (4x4 micro-tile per thread) ----
    float sc[4][4] = {};
#pragma unroll
    for (int kk = 0; kk < 64; kk += 4) {
      vf4 aq[4], bk[4];
#pragma unroll
      for (int d = 0; d < 4; ++d) {
        aq[d] = *(const vf4*)&Qs[ty * 4 + d][kk];
        bk[d] = *(const vf4*)&Ks[tx * 4 + d][kk];
      }
#pragma unroll
      for (int i = 0; i < 4; ++i)
#pragma unroll
        for (int j = 0; j < 4; ++j)
          sc[i][j] += aq[i][0] * bk[j][0] + aq[i][1] * bk[j][1]
                    + aq[i][2] * bk[j][2] + aq[i][3] * bk[j][3];
    }

    // ---- epilogue: point weights + mask; per-thread row maxes ----
#pragma unroll
    for (int i = 0; i < 4; ++i) {
      float rmax = -3.0e38f;
#pragma unroll
      for (int j = 0; j < 4; ++j) {
        float jf = (float)(j0 + tx * 4 + j);
        float w = 1.0f;
        if (jf == pbl[i]) w += pwbl[i];
        if (jf == pbr[i]) w += pwbr[i];
        if (jf == pal[i]) w += 1.0f - paf[i];
        if (jf == pal[i] + 1.0f) w += paf[i];
        float v = sc[i][j] * (SCALE * w);
        if (jf < pbl[i] || jf > pbr[i]) v = -1.0e8f;
        sc[i][j] = v;
        rmax = fmaxf(rmax, v);
      }
      red[ty * 4 + i][tx] = rmax;
    }
    __syncthreads();
    if (tid < 64) {
      float mt = red[tid][0];
#pragma unroll
      for (int t = 1; t < 16; ++t) mt = fmaxf(mt, red[tid][t]);
      float mo = m_s[tid];
      float mn = fmaxf(mo, mt);
      float a = __expf(mo - mn);     // exp(-huge) -> 0, no NaN
      alpha_s[tid] = a;
      m_s[tid] = mn;
      l_s[tid] *= a;
    }
    __syncthreads();

    // ---- P = exp(S - m); write transposed; row sums ----
#pragma unroll
    for (int i = 0; i < 4; ++i) {
      float mn = m_s[ty * 4 + i];
      float rsum = 0.0f;
#pragma unroll
      for (int j = 0; j < 4; ++j) {
        float p = __expf(sc[i][j] - mn);
        SsT[tx * 4 + j][ty * 4 + i] = p;
        rsum += p;
      }
      red[ty * 4 + i][tx] = rsum;
    }
    __syncthreads();
    if (tid < 64) {
      float s = 0.0f;
#pragma unroll
      for (int t = 0; t < 16; ++t) s += red[tid][t];
      l_s[tid] += s;
    }

    // ---- O = alpha*O + P @ V ----
    float al4[4];
#pragma unroll
    for (int i = 0; i < 4; ++i) al4[i] = alpha_s[ty * 4 + i];
#pragma unroll
    for (int i = 0; i < 4; ++i)
#pragma unroll
      for (int j = 0; j < 4; ++j) acc[i][j] *= al4[i];
#pragma unroll
    for (int j = 0; j < 64; j += 4) {
      vf4 pq[4], vv[4];
#pragma unroll
      for (int q = 0; q < 4; ++q) {
        pq[q] = *(const vf4*)&SsT[j + q][ty * 4];   // P[i=4ty..][j+q]
        vv[q] = *(const vf4*)&Vs[j + q][tx * 4];    // V[j+q][c=4tx..]
      }
#pragma unroll
      for (int q = 0; q < 4; ++q)
#pragma unroll
        for (int i = 0; i < 4; ++i)
#pragma unroll
          for (int c = 0; c < 4; ++c)
            acc[i][c] += pq[q][i] * vv[q][c];
    }
  }
  __syncthreads();   // final l_s writes visible

  // epilogue: out[b, i, h*64+c] = acc / l
#pragma unroll
  for (int i = 0; i < 4; ++i) {
    float linv = 1.0f / l_s[ty * 4 + i];
    size_t rowoff = (size_t)(b * T + i0 + ty * 4 + i) * E + h * HD;
    vf4 o;
#pragma unroll
    for (int j = 0; j < 4; ++j) o[j] = acc[i][j] * linv;
    *(vf4*)&attn_out[rowoff + tx * 4] = o;
  }
}

// =====================================================================
extern "C" void kernel_launch(void* const* d_in, const int* in_sizes, int n_in,
                              void* d_out, int out_size, void* d_ws, size_t ws_size,
                              hipStream_t stream)
{
  const float* x     = (const float*)d_in[0];
  const float* w_qkv = (const float*)d_in[1];
  const float* b_qkv = (const float*)d_in[2];
  const float* w_od  = (const float*)d_in[3];
  const float* b_od  = (const float*)d_in[4];
  const float* w_out = (const float*)d_in[5];
  const float* b_out = (const float*)d_in[6];
  float* out = (float*)d_out;

  float* ws   = (float*)d_ws;
  float* qkv  = ws;                                  // B*T*3E   = 6,291,456 f
  float* prm  = qkv + (size_t)B * T * 3 * E;         // 6*BH*T   =   196,608 f
  float* attn = prm + (size_t)6 * BH * T;            // B*T*E    = 2,097,152 f
  // total ~34.3 MB of d_ws

  // 1) qkv = x @ w_qkv + b_qkv
  gemm_bias<<<dim3(3 * E / 64, B * T / 64), 256, 0, stream>>>(
      x, w_qkv, b_qkv, qkv, B * T, E, 3 * E);

  // 2) od + window params
  od_params<<<dim3(B * T / 16), 256, 0, stream>>>(qkv, w_od, b_od, prm);

  // 3) attention
  flash_attn<<<dim3(T / 64, BH), 256, 0, stream>>>(qkv, prm, attn);

  // 4) out = attn @ w_out + b_out
  gemm_bias<<<dim3(E / 64, B * T / 64), 256, 0, stream>>>(
      attn, w_out, b_out, out, B * T, E, E);
}

// Round 2
// 254.231 us; speedup vs baseline: 7.3924x; 7.3924x over previous
//
#include <hip/hip_runtime.h>
#include <math.h>

typedef float vf4 __attribute__((ext_vector_type(4)));
typedef float f32x4 __attribute__((ext_vector_type(4)));
typedef short bf16x8 __attribute__((ext_vector_type(8)));
typedef short short4v __attribute__((ext_vector_type(4)));

constexpr int B = 2, T = 2048, E = 512, NH = 8, HD = 64;
constexpr int BH = B * NH;            // 16
constexpr int NT = BH * T;            // 32768
constexpr float SCALE = 0.125f;       // HD^-0.5

static __device__ __forceinline__ short f2bf(float f) {
  unsigned u = __float_as_uint(f);
  unsigned r = (u + 0x7fffu + ((u >> 16) & 1u)) >> 16;   // RNE
  return (short)r;
}

// =====================================================================
// casts
// =====================================================================
__global__ __launch_bounds__(256) void cast_x_bf16(
    const float* __restrict__ x, short* __restrict__ xb)
{
  int idx = (blockIdx.x * 256 + threadIdx.x) * 4;
  vf4 v = *(const vf4*)&x[idx];
  short4v o;
  o[0] = f2bf(v[0]); o[1] = f2bf(v[1]); o[2] = f2bf(v[2]); o[3] = f2bf(v[3]);
  *(short4v*)&xb[idx] = o;
}

// w_qkv [512][1536] fp32 -> wT [1536][512] bf16 (transposed), 32x32 LDS tiles
__global__ __launch_bounds__(256) void cast_wqkv_T(
    const float* __restrict__ w, short* __restrict__ wT)
{
  __shared__ float t[32][33];
  const int k0 = blockIdx.x * 32;     // 0..480
  const int n0 = blockIdx.y * 32;     // 0..1504
  const int c = threadIdx.x & 31, r = threadIdx.x >> 5;  // r: 0..7
#pragma unroll
  for (int p = 0; p < 4; ++p)
    t[r + p * 8][c] = w[(size_t)(k0 + r + p * 8) * 1536 + n0 + c];
  __syncthreads();
#pragma unroll
  for (int p = 0; p < 4; ++p)
    wT[(size_t)(n0 + r + p * 8) * 512 + k0 + c] = f2bf(t[c][r + p * 8]);
}

// Wc[k][c] = sum_m w_qkv[k][m] * w_od[m][c]  (m < 512, Q columns)
// bc[c] = sum_m b_qkv[m] * w_od[m][c] + b_od[c]
__global__ __launch_bounds__(256) void w_comb(
    const float* __restrict__ w_qkv, const float* __restrict__ b_qkv,
    const float* __restrict__ w_od, const float* __restrict__ b_od,
    float* __restrict__ Wc, float* __restrict__ bc)
{
  const int tid = threadIdx.x;
  if (blockIdx.x < 32) {
    const int k = blockIdx.x * 16 + (tid >> 4);
    const int c = tid & 15;
    float s = 0.0f;
    for (int m = 0; m < E; ++m)
      s += w_qkv[(size_t)k * 1536 + m] * w_od[m * 16 + c];
    Wc[k * 16 + c] = s;
  } else if (tid < 16) {
    const int c = tid;
    float s = b_od[c];
    for (int m = 0; m < E; ++m)
      s += b_qkv[m] * w_od[m * 16 + c];
    bc[c] = s;
  }
}

// =====================================================================
// qkv GEMM (bf16 MFMA): qkvb[M=4096][N=1536] = xb @ w_qkv (+bias),
// Q columns (<512) pre-scaled by SCALE. Tile 128x64, BK=32, 4 waves.
// =====================================================================
__global__ __launch_bounds__(256) void qkv_gemm_bf16(
    const short* __restrict__ xb, const short* __restrict__ wT,
    const float* __restrict__ bias, short* __restrict__ qkvb)
{
  __shared__ short As[128 * 40];   // [m][k] pitch 40
  __shared__ short Bt[64 * 40];    // [n][k] pitch 40

  const int tid = threadIdx.x;
  const int wave = tid >> 6, lane = tid & 63;
  const int quad = lane >> 4, l15 = lane & 15;
  const int wm = wave >> 1, wn = wave & 1;       // wave grid 2x2
  const int m0 = blockIdx.y * 128, n0 = blockIdx.x * 64;

  f32x4 acc[4][2];
#pragma unroll
  for (int mi = 0; mi < 4; ++mi)
#pragma unroll
    for (int ni = 0; ni < 2; ++ni) acc[mi][ni] = (f32x4){0, 0, 0, 0};

  const int ar = tid >> 2, akc = (tid & 3) * 8;   // A: +128 rows via 2nd iter
  const int br_ = tid >> 2, bkc = (tid & 3) * 8;  // B: 64 rows in one pass

#pragma unroll 1
  for (int k0 = 0; k0 < E; k0 += 32) {
    __syncthreads();
    *(bf16x8*)&As[ar * 40 + akc] =
        *(const bf16x8*)&xb[(size_t)(m0 + ar) * 512 + k0 + akc];
    *(bf16x8*)&As[(64 + ar) * 40 + akc] =
        *(const bf16x8*)&xb[(size_t)(m0 + 64 + ar) * 512 + k0 + akc];
    if (br_ < 64)
      *(bf16x8*)&Bt[br_ * 40 + bkc] =
          *(const bf16x8*)&wT[(size_t)(n0 + br_) * 512 + k0 + bkc];
    __syncthreads();

    bf16x8 aA[4], bB[2];
#pragma unroll
    for (int mi = 0; mi < 4; ++mi)
      aA[mi] = *(const bf16x8*)&As[(wm * 64 + mi * 16 + l15) * 40 + quad * 8];
#pragma unroll
    for (int ni = 0; ni < 2; ++ni)
      bB[ni] = *(const bf16x8*)&Bt[(wn * 32 + ni * 16 + l15) * 40 + quad * 8];
#pragma unroll
    for (int mi = 0; mi < 4; ++mi)
#pragma unroll
      for (int ni = 0; ni < 2; ++ni)
        acc[mi][ni] = __builtin_amdgcn_mfma_f32_16x16x32_bf16(
            aA[mi], bB[ni], acc[mi][ni], 0, 0, 0);
  }

#pragma unroll
  for (int mi = 0; mi < 4; ++mi)
#pragma unroll
    for (int ni = 0; ni < 2; ++ni)
#pragma unroll
      for (int r = 0; r < 4; ++r) {
        int row = m0 + wm * 64 + mi * 16 + quad * 4 + r;
        int col = n0 + wn * 32 + ni * 16 + l15;
        float v = acc[mi][ni][r] + bias[col];
        if (col < 512) v *= SCALE;            // fold SCALE into Q
        qkvb[(size_t)row * 1536 + col] = f2bf(v);
      }
}

// =====================================================================
// od (fp32 exact, from x and combined weights) + window params
// prm: 6 arrays of [BH*T]: bound_l, bound_r, w_bl, w_br, anchor_l, a_frac
// =====================================================================
__global__ __launch_bounds__(256) void od_params(
    const float* __restrict__ x, const float* __restrict__ Wc,
    const float* __restrict__ bc, float* __restrict__ prm)
{
  __shared__ float od_s[16][16];
  const int tid = threadIdx.x;
  const int r = tid >> 4, c = tid & 15;
  const int row = blockIdx.x * 16 + r;          // 0..B*T-1

  float sum = bc[c];
  const float* qr = x + (size_t)row * E;
  for (int k = 0; k < E; k += 4) {
    vf4 q = *(const vf4*)&qr[k];
    sum += q[0] * Wc[(k + 0) * 16 + c]
         + q[1] * Wc[(k + 1) * 16 + c]
         + q[2] * Wc[(k + 2) * 16 + c]
         + q[3] * Wc[(k + 3) * 16 + c];
  }
  od_s[r][c] = sum;
  __syncthreads();

  if (tid < 128) {
    const int rr = tid >> 3, h = tid & 7;
    const int grow = blockIdx.x * 16 + rr;
    const int b = grow / T, i = grow % T;
    float o = od_s[rr][h];
    float d = od_s[rr][h + 8];
    float offset   = tanhf(o) * (float)T;
    float duration = (float)T / (1.0f + expf(-d));
    float anchor = (float)i + offset;
    float start = anchor - duration;
    float end   = anchor + duration;
    float bl = floorf(start);
    float br = ceilf(end);
    float al = floorf(anchor);
    int idx = (b * NH + h) * T + i;
    prm[0 * NT + idx] = bl;
    prm[1 * NT + idx] = br;
    prm[2 * NT + idx] = bl - start;
    prm[3 * NT + idx] = end - br;
    prm[4 * NT + idx] = al;
    prm[5 * NT + idx] = anchor - al;
  }
}

// =====================================================================
// MFMA flash attention. Grid (T/64, BH), 256 thr = 4 waves x 16 queries.
// qkvb bf16 (Q pre-scaled by SCALE). Online softmax incl. masked -1e8
// positions (exact match to reference, incl. fully-masked -> uniform).
// =====================================================================
__global__ __launch_bounds__(256) void flash_attn_mfma(
    const short* __restrict__ qkvb, const float* __restrict__ prm,
    float* __restrict__ attn_out)
{
  __shared__ short Qs[64 * 72];
  __shared__ short Ks[64 * 72];
  __shared__ short Vt[64 * 72];   // [hd][key ^ ((hd>>3)<<3)] swizzled
  __shared__ short Ps[4][16 * 72];

  const int tid = threadIdx.x;
  const int wave = tid >> 6, lane = tid & 63;
  const int quad = lane >> 4, l15 = lane & 15;
  const int qt = blockIdx.x, bh = blockIdx.y;
  const int b = bh >> 3, h = bh & 7;
  const int i0 = qt * 64;

  // per-lane row params for rows quad*4 + r (wave-local rows wave*16+..)
  float bl[4], br[4], wbl[4], wbr[4], al[4], af[4];
  {
    int rowp = bh * T + i0 + wave * 16 + quad * 4;
#pragma unroll
    for (int r = 0; r < 4; ++r) {
      bl[r]  = prm[0 * NT + rowp + r];
      br[r]  = prm[1 * NT + rowp + r];
      wbl[r] = prm[2 * NT + rowp + r];
      wbr[r] = prm[3 * NT + rowp + r];
      al[r]  = prm[4 * NT + rowp + r];
      af[r]  = prm[5 * NT + rowp + r];
    }
  }

  // stage Q once: Qs[q][hd], 8 bf16 per thread per iter
  {
    const int rq = tid >> 3, cb = (tid & 7) * 8;
#pragma unroll
    for (int it = 0; it < 2; ++it) {
      int rr = it * 32 + rq;
      *(bf16x8*)&Qs[rr * 72 + cb] =
          *(const bf16x8*)&qkvb[(size_t)(b * T + i0 + rr) * 1536 + h * 64 + cb];
    }
  }

  f32x4 o[4];
#pragma unroll
  for (int c = 0; c < 4; ++c) o[c] = (f32x4){0, 0, 0, 0};
  float m_r[4] = {-3.0e38f, -3.0e38f, -3.0e38f, -3.0e38f};
  float l_r[4] = {0, 0, 0, 0};

  const int rq = tid >> 3, cb = (tid & 7) * 8;
  const int kw_sw = (cb >> 3) << 3;   // swizzle xor for this thread's V writes

#pragma unroll 1
  for (int kt = 0; kt < T / 64; ++kt) {
    const int j0 = kt * 64;
    __syncthreads();   // prior-iter Ks/Vt reads done
#pragma unroll
    for (int it = 0; it < 2; ++it) {
      int rr = it * 32 + rq;     // key index 0..63
      size_t base = (size_t)(b * T + j0 + rr) * 1536 + h * 64 + cb;
      *(bf16x8*)&Ks[rr * 72 + cb] = *(const bf16x8*)&qkvb[base + 512];
      bf16x8 v = *(const bf16x8*)&qkvb[base + 1024];
      int kw = rr ^ kw_sw;
#pragma unroll
      for (int j = 0; j < 8; ++j) Vt[(cb + j) * 72 + kw] = v[j];
    }
    __syncthreads();

    // ---- S = Q K^T ----
    bf16x8 aQ0 = *(const bf16x8*)&Qs[(wave * 16 + l15) * 72 + quad * 8];
    bf16x8 aQ1 = *(const bf16x8*)&Qs[(wave * 16 + l15) * 72 + 32 + quad * 8];
    f32x4 s[4];
#pragma unroll
    for (int nc = 0; nc < 4; ++nc) {
      const short* kb = &Ks[(nc * 16 + l15) * 72 + quad * 8];
      f32x4 a = (f32x4){0, 0, 0, 0};
      a = __builtin_amdgcn_mfma_f32_16x16x32_bf16(aQ0, *(const bf16x8*)&kb[0],  a, 0, 0, 0);
      a = __builtin_amdgcn_mfma_f32_16x16x32_bf16(aQ1, *(const bf16x8*)&kb[32], a, 0, 0, 0);
      s[nc] = a;
    }

    // ---- point weights + mask + row max ----
    float rmx[4] = {-3.0e38f, -3.0e38f, -3.0e38f, -3.0e38f};
    const float jf0 = (float)(j0 + l15);
#pragma unroll
    for (int nc = 0; nc < 4; ++nc) {
      float jf = jf0 + (float)(nc * 16);
#pragma unroll
      for (int r = 0; r < 4; ++r) {
        float w = 1.0f;
        w += (jf == bl[r]) ? wbl[r] : 0.0f;
        w += (jf == br[r]) ? wbr[r] : 0.0f;
        w += (jf == al[r]) ? (1.0f - af[r]) : 0.0f;
        w += (jf == al[r] + 1.0f) ? af[r] : 0.0f;
        float v = s[nc][r] * w;                       // SCALE already in Q
        v = (jf < bl[r] || jf > br[r]) ? -1.0e8f : v;
        s[nc][r] = v;
        rmx[r] = fmaxf(rmx[r], v);
      }
    }
#pragma unroll
    for (int d = 1; d < 16; d <<= 1)
#pragma unroll
      for (int r = 0; r < 4; ++r)
        rmx[r] = fmaxf(rmx[r], __shfl_xor(rmx[r], d));

    float alpha[4];
#pragma unroll
    for (int r = 0; r < 4; ++r) {
      float mn = fmaxf(m_r[r], rmx[r]);
      alpha[r] = __expf(m_r[r] - mn);   // exp(-huge) -> 0, no NaN
      m_r[r] = mn;
    }
    float rs[4] = {0, 0, 0, 0};
#pragma unroll
    for (int nc = 0; nc < 4; ++nc)
#pragma unroll
      for (int r = 0; r < 4; ++r) {
        float p = __expf(s[nc][r] - m_r[r]);
        s[nc][r] = p;
        rs[r] += p;
      }
#pragma unroll
    for (int d = 1; d < 16; d <<= 1)
#pragma unroll
      for (int r = 0; r < 4; ++r)
        rs[r] += __shfl_xor(rs[r], d);
#pragma unroll
    for (int r = 0; r < 4; ++r) l_r[r] = l_r[r] * alpha[r] + rs[r];
#pragma unroll
    for (int c = 0; c < 4; ++c)
#pragma unroll
      for (int r = 0; r < 4; ++r) o[c][r] *= alpha[r];

    // ---- P -> LDS (A-layout source), bf16 ----
#pragma unroll
    for (int nc = 0; nc < 4; ++nc)
#pragma unroll
      for (int r = 0; r < 4; ++r)
        Ps[wave][(quad * 4 + r) * 72 + nc * 16 + l15] = f2bf(s[nc][r]);
    __syncthreads();

    // ---- O += P V ----
    bf16x8 aP0 = *(const bf16x8*)&Ps[wave][l15 * 72 + quad * 8];
    bf16x8 aP1 = *(const bf16x8*)&Ps[wave][l15 * 72 + 32 + quad * 8];
#pragma unroll
    for (int c = 0; c < 4; ++c) {
      int hd = c * 16 + l15;
      int g = (hd >> 3) & 7;
      const short* vb = &Vt[hd * 72];
      int blk0 = (quad) ^ g;
      int blk1 = (4 + quad) ^ g;
      o[c] = __builtin_amdgcn_mfma_f32_16x16x32_bf16(
          aP0, *(const bf16x8*)&vb[blk0 * 8], o[c], 0, 0, 0);
      o[c] = __builtin_amdgcn_mfma_f32_16x16x32_bf16(
          aP1, *(const bf16x8*)&vb[blk1 * 8], o[c], 0, 0, 0);
    }
  }

  // epilogue: attn_out[b, i, h*64+col] = o / l
#pragma unroll
  for (int r = 0; r < 4; ++r) {
    float linv = 1.0f / l_r[r];
    int row = i0 + wave * 16 + quad * 4 + r;
    size_t base = (size_t)(b * T + row) * E + h * 64;
#pragma unroll
    for (int c = 0; c < 4; ++c)
      attn_out[base + c * 16 + l15] = o[c][r] * linv;
  }
}

// =====================================================================
// fp32 GEMM + bias (out projection) — round-1 kernel, known good.
// =====================================================================
__global__ __launch_bounds__(256) void gemm_bias(
    const float* __restrict__ A, const float* __restrict__ W,
    const float* __restrict__ bias, float* __restrict__ C,
    int M, int K, int N)
{
  __shared__ float Ast[16][68];
  __shared__ float Bs[16][68];

  const int tid = threadIdx.x;
  const int tx = tid & 15, ty = tid >> 4;
  const int m0 = blockIdx.y * 64, n0 = blockIdx.x * 64;

  const int ar = tid >> 2;
  const int ak = (tid & 3) * 4;
  const int bk = tid >> 4;
  const int bc = (tid & 15) * 4;

  float acc[4][4] = {};

  for (int k0 = 0; k0 < K; k0 += 16) {
    vf4 av = *(const vf4*)&A[(size_t)(m0 + ar) * K + k0 + ak];
    vf4 wv = *(const vf4*)&W[(size_t)(k0 + bk) * N + n0 + bc];
    __syncthreads();
    Ast[ak + 0][ar] = av[0];
    Ast[ak + 1][ar] = av[1];
    Ast[ak + 2][ar] = av[2];
    Ast[ak + 3][ar] = av[3];
    *(vf4*)&Bs[bk][bc] = wv;
    __syncthreads();
#pragma unroll
    for (int kk = 0; kk < 16; ++kk) {
      vf4 a = *(const vf4*)&Ast[kk][ty * 4];
      vf4 b = *(const vf4*)&Bs[kk][tx * 4];
#pragma unroll
      for (int i = 0; i < 4; ++i)
#pragma unroll
        for (int j = 0; j < 4; ++j)
          acc[i][j] += a[i] * b[j];
    }
  }

#pragma unroll
  for (int i = 0; i < 4; ++i) {
    size_t row = m0 + ty * 4 + i;
#pragma unroll
    for (int j = 0; j < 4; ++j) {
      int col = n0 + tx * 4 + j;
      C[row * N + col] = acc[i][j] + bias[col];
    }
  }
}

// =====================================================================
extern "C" void kernel_launch(void* const* d_in, const int* in_sizes, int n_in,
                              void* d_out, int out_size, void* d_ws, size_t ws_size,
                              hipStream_t stream)
{
  const float* x     = (const float*)d_in[0];
  const float* w_qkv = (const float*)d_in[1];
  const float* b_qkv = (const float*)d_in[2];
  const float* w_od  = (const float*)d_in[3];
  const float* b_od  = (const float*)d_in[4];
  const float* w_out = (const float*)d_in[5];
  const float* b_out = (const float*)d_in[6];
  float* out = (float*)d_out;

  char* w = (char*)d_ws;
  short* xb   = (short*)w;            w += (size_t)B * T * E * 2;          // 4 MB
  short* wT   = (short*)w;            w += (size_t)E * 3 * E * 2;          // 1.5 MB
  short* qkvb = (short*)w;            w += (size_t)B * T * 3 * E * 2;      // 12.6 MB
  float* Wc   = (float*)w;            w += (size_t)E * 16 * 4;             // 32 KB
  float* bc   = (float*)w;            w += 64;
  float* prm  = (float*)w;            w += (size_t)6 * NT * 4;             // 786 KB
  float* attn = (float*)w;            w += (size_t)B * T * E * 4;          // 8.4 MB

  // 1) casts + combined od weights (fp32-exact od path)
  cast_x_bf16<<<dim3(B * T * E / 1024), 256, 0, stream>>>(x, xb);
  cast_wqkv_T<<<dim3(E / 32, 3 * E / 32), 256, 0, stream>>>(w_qkv, wT);
  w_comb<<<dim3(33), 256, 0, stream>>>(w_qkv, b_qkv, w_od, b_od, Wc, bc);

  // 2) qkv = x @ w_qkv + b_qkv  (bf16 MFMA, Q pre-scaled)
  qkv_gemm_bf16<<<dim3(3 * E / 64, B * T / 128), 256, 0, stream>>>(
      xb, wT, b_qkv, qkvb);

  // 3) window params (fp32 exact)
  od_params<<<dim3(B * T / 16), 256, 0, stream>>>(x, Wc, bc, prm);

  // 4) attention (bf16 MFMA flash)
  flash_attn_mfma<<<dim3(T / 64, BH), 256, 0, stream>>>(qkvb, prm, attn);

  // 5) out = attn @ w_out + b_out (fp32)
  gemm_bias<<<dim3(E / 64, B * T / 64), 256, 0, stream>>>(
      attn, w_out, b_out, out, B * T, E, E);
}

// Round 3
// 197.314 us; speedup vs baseline: 9.5248x; 1.2885x over previous
//
#include <hip/hip_runtime.h>
#include <math.h>

typedef float vf4 __attribute__((ext_vector_type(4)));
typedef float f32x4 __attribute__((ext_vector_type(4)));
typedef short bf16x8 __attribute__((ext_vector_type(8)));
typedef short short4v __attribute__((ext_vector_type(4)));

constexpr int B = 2, T = 2048, E = 512, NH = 8, HD = 64;
constexpr int BH = B * NH;            // 16
constexpr int NT = BH * T;            // 32768
constexpr float SCALE = 0.125f;       // HD^-0.5

static __device__ __forceinline__ short f2bf(float f) {
  unsigned u = __float_as_uint(f);
  unsigned r = (u + 0x7fffu + ((u >> 16) & 1u)) >> 16;   // RNE
  return (short)r;
}

// =====================================================================
// casts
// =====================================================================
__global__ __launch_bounds__(256) void cast_x_bf16(
    const float* __restrict__ x, short* __restrict__ xb)
{
  int idx = (blockIdx.x * 256 + threadIdx.x) * 4;
  vf4 v = *(const vf4*)&x[idx];
  short4v o;
  o[0] = f2bf(v[0]); o[1] = f2bf(v[1]); o[2] = f2bf(v[2]); o[3] = f2bf(v[3]);
  *(short4v*)&xb[idx] = o;
}

// w [512][N] fp32 -> wT [N][512] bf16 (transposed), 32x32 LDS tiles
__global__ __launch_bounds__(256) void cast_w_T(
    const float* __restrict__ w, short* __restrict__ wT, int N)
{
  __shared__ float t[32][33];
  const int k0 = blockIdx.x * 32;
  const int n0 = blockIdx.y * 32;
  const int c = threadIdx.x & 31, r = threadIdx.x >> 5;  // r: 0..7
#pragma unroll
  for (int p = 0; p < 4; ++p)
    t[r + p * 8][c] = w[(size_t)(k0 + r + p * 8) * N + n0 + c];
  __syncthreads();
#pragma unroll
  for (int p = 0; p < 4; ++p)
    wT[(size_t)(n0 + r + p * 8) * 512 + k0 + c] = f2bf(t[c][r + p * 8]);
}

// Wc[k][c] = sum_m w_qkv[k][m] * w_od[m][c]  (m < 512, Q columns)
// bc[c] = sum_m b_qkv[m] * w_od[m][c] + b_od[c]
__global__ __launch_bounds__(256) void w_comb(
    const float* __restrict__ w_qkv, const float* __restrict__ b_qkv,
    const float* __restrict__ w_od, const float* __restrict__ b_od,
    float* __restrict__ Wc, float* __restrict__ bc)
{
  const int tid = threadIdx.x;
  if (blockIdx.x < 32) {
    const int k = blockIdx.x * 16 + (tid >> 4);
    const int c = tid & 15;
    float s = 0.0f;
    for (int m = 0; m < E; ++m)
      s += w_qkv[(size_t)k * 1536 + m] * w_od[m * 16 + c];
    Wc[k * 16 + c] = s;
  } else if (tid < 16) {
    const int c = tid;
    float s = b_od[c];
    for (int m = 0; m < E; ++m)
      s += b_qkv[m] * w_od[m * 16 + c];
    bc[c] = s;
  }
}

// =====================================================================
// qkv GEMM (bf16 MFMA): qkvb[4096][1536] = xb @ w_qkv (+bias),
// Q columns (<512) pre-scaled by SCALE. Tile 128x64, BK=32, 4 waves.
// =====================================================================
__global__ __launch_bounds__(256) void qkv_gemm_bf16(
    const short* __restrict__ xb, const short* __restrict__ wT,
    const float* __restrict__ bias, short* __restrict__ qkvb)
{
  __shared__ short As[128 * 40];   // [m][k] pitch 40
  __shared__ short Bt[64 * 40];    // [n][k] pitch 40

  const int tid = threadIdx.x;
  const int wave = tid >> 6, lane = tid & 63;
  const int quad = lane >> 4, l15 = lane & 15;
  const int wm = wave >> 1, wn = wave & 1;
  const int m0 = blockIdx.y * 128, n0 = blockIdx.x * 64;

  f32x4 acc[4][2];
#pragma unroll
  for (int mi = 0; mi < 4; ++mi)
#pragma unroll
    for (int ni = 0; ni < 2; ++ni) acc[mi][ni] = (f32x4){0, 0, 0, 0};

  const int ar = tid >> 2, akc = (tid & 3) * 8;
  const int br_ = tid >> 2, bkc = (tid & 3) * 8;

#pragma unroll 1
  for (int k0 = 0; k0 < E; k0 += 32) {
    __syncthreads();
    *(bf16x8*)&As[ar * 40 + akc] =
        *(const bf16x8*)&xb[(size_t)(m0 + ar) * 512 + k0 + akc];
    *(bf16x8*)&As[(64 + ar) * 40 + akc] =
        *(const bf16x8*)&xb[(size_t)(m0 + 64 + ar) * 512 + k0 + akc];
    if (br_ < 64)
      *(bf16x8*)&Bt[br_ * 40 + bkc] =
          *(const bf16x8*)&wT[(size_t)(n0 + br_) * 512 + k0 + bkc];
    __syncthreads();

    bf16x8 aA[4], bB[2];
#pragma unroll
    for (int mi = 0; mi < 4; ++mi)
      aA[mi] = *(const bf16x8*)&As[(wm * 64 + mi * 16 + l15) * 40 + quad * 8];
#pragma unroll
    for (int ni = 0; ni < 2; ++ni)
      bB[ni] = *(const bf16x8*)&Bt[(wn * 32 + ni * 16 + l15) * 40 + quad * 8];
#pragma unroll
    for (int mi = 0; mi < 4; ++mi)
#pragma unroll
      for (int ni = 0; ni < 2; ++ni)
        acc[mi][ni] = __builtin_amdgcn_mfma_f32_16x16x32_bf16(
            aA[mi], bB[ni], acc[mi][ni], 0, 0, 0);
  }

#pragma unroll
  for (int mi = 0; mi < 4; ++mi)
#pragma unroll
    for (int ni = 0; ni < 2; ++ni)
#pragma unroll
      for (int r = 0; r < 4; ++r) {
        int row = m0 + wm * 64 + mi * 16 + quad * 4 + r;
        int col = n0 + wn * 32 + ni * 16 + l15;
        float v = acc[mi][ni][r] + bias[col];
        if (col < 512) v *= SCALE;
        qkvb[(size_t)row * 1536 + col] = f2bf(v);
      }
}

// =====================================================================
// od (fp32 exact) + window params.
// prm: 7 arrays of [NT]: bl, br, w_bl, w_br, anchor_l, a_frac, rowscale
// Fully-masked rows (window outside [0,T-1]) are rewritten to window
// [0,T-1] with rowscale=0 -> all scores 0 -> uniform softmax over all T,
// exactly matching the reference's all -1e8 -> uniform behavior.
// =====================================================================
__global__ __launch_bounds__(256) void od_params(
    const float* __restrict__ x, const float* __restrict__ Wc,
    const float* __restrict__ bc, float* __restrict__ prm)
{
  __shared__ float od_s[16][16];
  const int tid = threadIdx.x;
  const int r = tid >> 4, c = tid & 15;
  const int row = blockIdx.x * 16 + r;

  float sum = bc[c];
  const float* qr = x + (size_t)row * E;
  for (int k = 0; k < E; k += 4) {
    vf4 q = *(const vf4*)&qr[k];
    sum += q[0] * Wc[(k + 0) * 16 + c]
         + q[1] * Wc[(k + 1) * 16 + c]
         + q[2] * Wc[(k + 2) * 16 + c]
         + q[3] * Wc[(k + 3) * 16 + c];
  }
  od_s[r][c] = sum;
  __syncthreads();

  if (tid < 128) {
    const int rr = tid >> 3, h = tid & 7;
    const int grow = blockIdx.x * 16 + rr;
    const int b = grow / T, i = grow % T;
    float o = od_s[rr][h];
    float d = od_s[rr][h + 8];
    float offset   = tanhf(o) * (float)T;
    float duration = (float)T / (1.0f + expf(-d));
    float anchor = (float)i + offset;
    float start = anchor - duration;
    float end   = anchor + duration;
    float bl = floorf(start);
    float br = ceilf(end);
    float al = floorf(anchor);
    float wbl = bl - start;
    float wbr = end - br;
    float af  = anchor - al;
    float rsc = 1.0f;
    if (br < 0.0f || bl > (float)(T - 1)) {
      bl = 0.0f; br = (float)(T - 1);
      wbl = 0.0f; wbr = 0.0f; al = -5.0f; af = 0.0f;
      rsc = 0.0f;
    }
    int idx = (b * NH + h) * T + i;
    prm[0 * NT + idx] = bl;
    prm[1 * NT + idx] = br;
    prm[2 * NT + idx] = wbl;
    prm[3 * NT + idx] = wbr;
    prm[4 * NT + idx] = al;
    prm[5 * NT + idx] = af;
    prm[6 * NT + idx] = rsc;
  }
}

// =====================================================================
// MFMA flash attention, fixed-max softmax, K-split 2-way + tile skip.
// Grid (T/64, BH, 2). Writes unnormalized Opart (fp32) and lpart.
// Masked positions -> score -30 -> exp ~ 9e-14 (ref: exactly 0) —
// negligible; fully-masked rows handled via rowscale (see od_params).
// =====================================================================
__global__ __launch_bounds__(256) void flash_attn_mfma2(
    const short* __restrict__ qkvb, const float* __restrict__ prm,
    float* __restrict__ Opart, float* __restrict__ lpart)
{
  __shared__ short Qs[64 * 72];
  __shared__ short Ks[64 * 72];
  __shared__ short Vt[64 * 72];   // [hd][key ^ ((hd>>3)<<3)] swizzled
  __shared__ short Ps[4][16 * 72];
  __shared__ float u_s[8];

  const int tid = threadIdx.x;
  const int wave = tid >> 6, lane = tid & 63;
  const int quad = lane >> 4, l15 = lane & 15;
  const int qt = blockIdx.x, bh = blockIdx.y, ks = blockIdx.z;
  const int b = bh >> 3, h = bh & 7;
  const int i0 = qt * 64;

  float bl[4], br[4], wbl[4], wbr[4], al[4], af[4], rsc[4];
  {
    int rowp = bh * T + i0 + wave * 16 + quad * 4;
#pragma unroll
    for (int r = 0; r < 4; ++r) {
      bl[r]  = prm[0 * NT + rowp + r];
      br[r]  = prm[1 * NT + rowp + r];
      wbl[r] = prm[2 * NT + rowp + r];
      wbr[r] = prm[3 * NT + rowp + r];
      al[r]  = prm[4 * NT + rowp + r];
      af[r]  = prm[5 * NT + rowp + r];
      rsc[r] = prm[6 * NT + rowp + r];
    }
  }

  // block union of windows -> K-tile range for this half
  float bmn = fminf(fminf(bl[0], bl[1]), fminf(bl[2], bl[3]));
  float bmx = fmaxf(fmaxf(br[0], br[1]), fmaxf(br[2], br[3]));
#pragma unroll
  for (int d = 16; d < 64; d <<= 1) {
    bmn = fminf(bmn, __shfl_xor(bmn, d));
    bmx = fmaxf(bmx, __shfl_xor(bmx, d));
  }
  if (lane == 0) { u_s[wave * 2] = bmn; u_s[wave * 2 + 1] = bmx; }

  // stage Q while union settles
  {
    const int rq = tid >> 3, cb = (tid & 7) * 8;
#pragma unroll
    for (int it = 0; it < 2; ++it) {
      int rr = it * 32 + rq;
      *(bf16x8*)&Qs[rr * 72 + cb] =
          *(const bf16x8*)&qkvb[(size_t)(b * T + i0 + rr) * 1536 + h * 64 + cb];
    }
  }
  __syncthreads();
  bmn = fminf(fminf(u_s[0], u_s[2]), fminf(u_s[4], u_s[6]));
  bmx = fmaxf(fmaxf(u_s[1], u_s[3]), fmaxf(u_s[5], u_s[7]));
  const int ktlo = max(ks * 16, max(((int)bmn) >> 6, 0));
  const int kthi = min(ks * 16 + 15, min(((int)bmx) >> 6, T / 64 - 1));

  f32x4 o[4];
#pragma unroll
  for (int c = 0; c < 4; ++c) o[c] = (f32x4){0, 0, 0, 0};
  float lacc[4] = {0, 0, 0, 0};

  const int rq = tid >> 3, cb = (tid & 7) * 8;
  const int kw_sw = (cb >> 3) << 3;

#pragma unroll 1
  for (int kt = ktlo; kt <= kthi; ++kt) {
    const int j0 = kt * 64;
    __syncthreads();   // prior-iter Ks/Vt/Ps reads done
#pragma unroll
    for (int it = 0; it < 2; ++it) {
      int rr = it * 32 + rq;
      size_t base = (size_t)(b * T + j0 + rr) * 1536 + h * 64 + cb;
      *(bf16x8*)&Ks[rr * 72 + cb] = *(const bf16x8*)&qkvb[base + 512];
      bf16x8 v = *(const bf16x8*)&qkvb[base + 1024];
      int kw = rr ^ kw_sw;
#pragma unroll
      for (int j = 0; j < 8; ++j) Vt[(cb + j) * 72 + kw] = v[j];
    }
    __syncthreads();

    // ---- S = Q K^T ----
    bf16x8 aQ0 = *(const bf16x8*)&Qs[(wave * 16 + l15) * 72 + quad * 8];
    bf16x8 aQ1 = *(const bf16x8*)&Qs[(wave * 16 + l15) * 72 + 32 + quad * 8];
    f32x4 s[4];
#pragma unroll
    for (int nc = 0; nc < 4; ++nc) {
      const short* kb = &Ks[(nc * 16 + l15) * 72 + quad * 8];
      f32x4 a = (f32x4){0, 0, 0, 0};
      a = __builtin_amdgcn_mfma_f32_16x16x32_bf16(aQ0, *(const bf16x8*)&kb[0],  a, 0, 0, 0);
      a = __builtin_amdgcn_mfma_f32_16x16x32_bf16(aQ1, *(const bf16x8*)&kb[32], a, 0, 0, 0);
      s[nc] = a;
    }

    // ---- point weights + mask + exp (fixed max), accumulate l ----
    const float jf0 = (float)(j0 + l15);
#pragma unroll
    for (int nc = 0; nc < 4; ++nc) {
      float jf = jf0 + (float)(nc * 16);
#pragma unroll
      for (int r = 0; r < 4; ++r) {
        float w = 1.0f;
        w += (jf == bl[r]) ? wbl[r] : 0.0f;
        w += (jf == br[r]) ? wbr[r] : 0.0f;
        w += (jf == al[r]) ? (1.0f - af[r]) : 0.0f;
        w += (jf == al[r] + 1.0f) ? af[r] : 0.0f;
        float v = s[nc][r] * w * rsc[r];              // SCALE already in Q
        v = (jf < bl[r] || jf > br[r]) ? -30.0f : v;
        float p = __expf(v);
        lacc[r] += p;
        Ps[wave][(quad * 4 + r) * 72 + nc * 16 + l15] = f2bf(p);
      }
    }
    __syncthreads();

    // ---- O += P V ----
    bf16x8 aP0 = *(const bf16x8*)&Ps[wave][l15 * 72 + quad * 8];
    bf16x8 aP1 = *(const bf16x8*)&Ps[wave][l15 * 72 + 32 + quad * 8];
#pragma unroll
    for (int c = 0; c < 4; ++c) {
      int hd = c * 16 + l15;
      int g = (hd >> 3) & 7;
      const short* vb = &Vt[hd * 72];
      int blk0 = (quad) ^ g;
      int blk1 = (4 + quad) ^ g;
      o[c] = __builtin_amdgcn_mfma_f32_16x16x32_bf16(
          aP0, *(const bf16x8*)&vb[blk0 * 8], o[c], 0, 0, 0);
      o[c] = __builtin_amdgcn_mfma_f32_16x16x32_bf16(
          aP1, *(const bf16x8*)&vb[blk1 * 8], o[c], 0, 0, 0);
    }
  }

  // final l reduction across the 16 column-lanes (once, not per tile)
#pragma unroll
  for (int d = 1; d < 16; d <<= 1)
#pragma unroll
    for (int r = 0; r < 4; ++r)
      lacc[r] += __shfl_xor(lacc[r], d);

  const int rowb = i0 + wave * 16 + quad * 4;
  if (l15 == 0) {
#pragma unroll
    for (int r = 0; r < 4; ++r)
      lpart[ks * NT + bh * T + rowb + r] = lacc[r];
  }
#pragma unroll
  for (int r = 0; r < 4; ++r) {
    size_t base = (size_t)ks * (B * T * E) + (size_t)(b * T + rowb + r) * E + h * 64;
#pragma unroll
    for (int c = 0; c < 4; ++c)
      Opart[base + c * 16 + l15] = o[c][r];
  }
}

// =====================================================================
// attn = (O0 + O1) / (l0 + l1), cast bf16
// =====================================================================
__global__ __launch_bounds__(256) void combine_attn(
    const float* __restrict__ Opart, const float* __restrict__ lpart,
    short* __restrict__ attnb)
{
  int base = (blockIdx.x * 256 + threadIdx.x) * 4;
  int row = base >> 9;            // / 512
  int c = base & 511;
  int h = c >> 6;
  int b = row >> 11;              // / T
  int i = row & (T - 1);
  int lidx = ((b << 3) + h) * T + i;
  float l = lpart[lidx] + lpart[NT + lidx];
  float inv = 1.0f / l;
  vf4 o0 = *(const vf4*)&Opart[base];
  vf4 o1 = *(const vf4*)&Opart[(size_t)(B * T * E) + base];
  short4v ov;
#pragma unroll
  for (int j = 0; j < 4; ++j) ov[j] = f2bf((o0[j] + o1[j]) * inv);
  *(short4v*)&attnb[base] = ov;
}

// =====================================================================
// out GEMM (bf16 MFMA): out[4096][512] = attnb @ w_out + b_out (fp32 out)
// Tile 64x64, BK=32, 4 waves (2x2, each 32x32). Grid (8, 64).
// =====================================================================
__global__ __launch_bounds__(256) void out_gemm_bf16(
    const short* __restrict__ Ab, const short* __restrict__ wT,
    const float* __restrict__ bias, float* __restrict__ Co)
{
  __shared__ short As[64 * 40];
  __shared__ short Bt[64 * 40];

  const int tid = threadIdx.x;
  const int wave = tid >> 6, lane = tid & 63;
  const int quad = lane >> 4, l15 = lane & 15;
  const int wm = wave >> 1, wn = wave & 1;
  const int m0 = blockIdx.y * 64, n0 = blockIdx.x * 64;

  f32x4 acc[2][2];
#pragma unroll
  for (int mi = 0; mi < 2; ++mi)
#pragma unroll
    for (int ni = 0; ni < 2; ++ni) acc[mi][ni] = (f32x4){0, 0, 0, 0};

  const int ar = tid >> 2, akc = (tid & 3) * 8;

#pragma unroll 1
  for (int k0 = 0; k0 < E; k0 += 32) {
    __syncthreads();
    *(bf16x8*)&As[ar * 40 + akc] =
        *(const bf16x8*)&Ab[(size_t)(m0 + ar) * 512 + k0 + akc];
    *(bf16x8*)&Bt[ar * 40 + akc] =
        *(const bf16x8*)&wT[(size_t)(n0 + ar) * 512 + k0 + akc];
    __syncthreads();

    bf16x8 aA[2], bB[2];
#pragma unroll
    for (int mi = 0; mi < 2; ++mi)
      aA[mi] = *(const bf16x8*)&As[(wm * 32 + mi * 16 + l15) * 40 + quad * 8];
#pragma unroll
    for (int ni = 0; ni < 2; ++ni)
      bB[ni] = *(const bf16x8*)&Bt[(wn * 32 + ni * 16 + l15) * 40 + quad * 8];
#pragma unroll
    for (int mi = 0; mi < 2; ++mi)
#pragma unroll
      for (int ni = 0; ni < 2; ++ni)
        acc[mi][ni] = __builtin_amdgcn_mfma_f32_16x16x32_bf16(
            aA[mi], bB[ni], acc[mi][ni], 0, 0, 0);
  }

#pragma unroll
  for (int mi = 0; mi < 2; ++mi)
#pragma unroll
    for (int ni = 0; ni < 2; ++ni)
#pragma unroll
      for (int r = 0; r < 4; ++r) {
        int row = m0 + wm * 32 + mi * 16 + quad * 4 + r;
        int col = n0 + wn * 32 + ni * 16 + l15;
        Co[(size_t)row * 512 + col] = acc[mi][ni][r] + bias[col];
      }
}

// =====================================================================
extern "C" void kernel_launch(void* const* d_in, const int* in_sizes, int n_in,
                              void* d_out, int out_size, void* d_ws, size_t ws_size,
                              hipStream_t stream)
{
  const float* x     = (const float*)d_in[0];
  const float* w_qkv = (const float*)d_in[1];
  const float* b_qkv = (const float*)d_in[2];
  const float* w_od  = (const float*)d_in[3];
  const float* b_od  = (const float*)d_in[4];
  const float* w_out = (const float*)d_in[5];
  const float* b_out = (const float*)d_in[6];
  float* out = (float*)d_out;

  char* w = (char*)d_ws;
  short* xb    = (short*)w;  w += (size_t)B * T * E * 2;          // 4 MB
  short* wTq   = (short*)w;  w += (size_t)E * 3 * E * 2;          // 1.5 MB
  short* wTo   = (short*)w;  w += (size_t)E * E * 2;              // 0.5 MB
  short* qkvb  = (short*)w;  w += (size_t)B * T * 3 * E * 2;      // 12.6 MB
  float* Wc    = (float*)w;  w += (size_t)E * 16 * 4;             // 32 KB
  float* bc    = (float*)w;  w += 256;
  float* prm   = (float*)w;  w += (size_t)7 * NT * 4;             // 896 KB
  float* Opart = (float*)w;  w += (size_t)2 * B * T * E * 4;      // 16.8 MB
  float* lpart = (float*)w;  w += (size_t)2 * NT * 4;             // 256 KB
  short* attnb = (short*)w;  w += (size_t)B * T * E * 2;          // 4 MB

  // 1) casts + combined od weights
  cast_x_bf16<<<dim3(B * T * E / 1024), 256, 0, stream>>>(x, xb);
  cast_w_T<<<dim3(E / 32, 3 * E / 32), 256, 0, stream>>>(w_qkv, wTq, 3 * E);
  cast_w_T<<<dim3(E / 32, E / 32), 256, 0, stream>>>(w_out, wTo, E);
  w_comb<<<dim3(33), 256, 0, stream>>>(w_qkv, b_qkv, w_od, b_od, Wc, bc);

  // 2) qkv = x @ w_qkv + b_qkv  (bf16 MFMA, Q pre-scaled)
  qkv_gemm_bf16<<<dim3(3 * E / 64, B * T / 128), 256, 0, stream>>>(
      xb, wTq, b_qkv, qkvb);

  // 3) window params (fp32 exact)
  od_params<<<dim3(B * T / 16), 256, 0, stream>>>(x, Wc, bc, prm);

  // 4) attention (bf16 MFMA, K-split 2-way)
  flash_attn_mfma2<<<dim3(T / 64, BH, 2), 256, 0, stream>>>(
      qkvb, prm, Opart, lpart);

  // 5) combine partials -> attn bf16
  combine_attn<<<dim3(B * T * E / 1024), 256, 0, stream>>>(Opart, lpart, attnb);

  // 6) out = attn @ w_out + b_out (bf16 MFMA, fp32 out)
  out_gemm_bf16<<<dim3(E / 64, B * T / 64), 256, 0, stream>>>(
      attnb, wTo, b_out, out);
}